// Round 1
// baseline (257.650 us; speedup 1.0000x reference)
//
#include <hip/hip_runtime.h>
#include <stdint.h>

#define BATCH 8
#define SEQ 2048
#define DIM 1024
#define MTOT (BATCH * SEQ)   // 16384
#define NCHUNK 32
#define CLEN (SEQ / NCHUNK)  // 64

typedef __attribute__((ext_vector_type(8))) short short8;
typedef __attribute__((ext_vector_type(4))) float floatx4;

// ---------- helpers ----------

__device__ __forceinline__ unsigned short f2bf(float f) {
  union { float f; unsigned u; } c; c.f = f;
  unsigned u = c.u;
  // round-to-nearest-even (inputs are finite/normal here)
  return (unsigned short)((u + 0x7FFFu + ((u >> 16) & 1u)) >> 16);
}
__device__ __forceinline__ float bf2f(unsigned short h) {
  union { unsigned u; float f; } c; c.u = ((unsigned)h) << 16;
  return c.f;
}

// async global->LDS, 16B per lane. LDS dest is wave-uniform base; HW writes
// lane i at base + i*16 (guide §5 caveat: layout must be lane-contiguous).
__device__ __forceinline__ void gll16(const void* g, void* l) {
  __builtin_amdgcn_global_load_lds(
      (__attribute__((address_space(1))) void*)(uintptr_t)g,
      (__attribute__((address_space(3))) void*)(uintptr_t)l,
      16, 0, 0);
}

// ---------- cast fp32 -> bf16, 8 elems/thread ----------

__global__ __launch_bounds__(256) void cast_f32_bf16_kernel(
    const float* __restrict__ src, unsigned short* __restrict__ dst, int n8) {
  int i = blockIdx.x * 256 + threadIdx.x;
  if (i >= n8) return;
  const float4* s4 = (const float4*)src;
  float4 a = s4[2 * i], b = s4[2 * i + 1];
  uint4 o;
  o.x = (unsigned)f2bf(a.x) | ((unsigned)f2bf(a.y) << 16);
  o.y = (unsigned)f2bf(a.z) | ((unsigned)f2bf(a.w) << 16);
  o.z = (unsigned)f2bf(b.x) | ((unsigned)f2bf(b.y) << 16);
  o.w = (unsigned)f2bf(b.z) | ((unsigned)f2bf(b.w) << 16);
  ((uint4*)dst)[i] = o;
}

// ---------- NT GEMM: C[m][n] = sum_k A[m][k]*B[n][k]  (both row-major, K contig)
// 128x128 tile, BK=64, 256 threads (4 waves, each 64x64), 16x16x32 bf16 MFMA.

template <bool OUT_BF16>
__global__ __launch_bounds__(256) void gemm_nt(
    const unsigned short* __restrict__ A,  // [M x K] bf16
    const unsigned short* __restrict__ B,  // [N x K] bf16
    void* __restrict__ Cp,                 // bf16 [MxN] or fp32 [MxN]
    const float* __restrict__ bias,        // used when !OUT_BF16
    int K, int N) {
  __shared__ unsigned short sA[128 * 64];
  __shared__ unsigned short sB[128 * 64];

  const int tid = threadIdx.x;
  const int wave = tid >> 6, lane = tid & 63;
  const size_t m0 = (size_t)blockIdx.y * 128;
  const int n0 = blockIdx.x * 128;

  floatx4 acc[4][4] = {};

  // staging: per round r (4 rounds/tile), wave w covers rows r*32 + w*8 + lane/8,
  // 16B (8 bf16) per lane; LDS layout [row][k] row-major, 64 bf16/row, no pad
  // so that base + lane*16 == (row,col) exactly.
  const int srow = wave * 8 + (lane >> 3);
  const int scol = (lane & 7) * 8;
  const unsigned short* gA = A + (m0 + srow) * (size_t)K + scol;
  const unsigned short* gB = B + ((size_t)n0 + srow) * (size_t)K + scol;
  unsigned short* lA = sA + wave * 8 * 64;  // wave-uniform LDS base
  unsigned short* lB = sB + wave * 8 * 64;

  // fragment addressing: A-operand lane l holds A[m=l&15][k = (l>>4)*8 + j]
  const int fr = lane & 15;
  const int fk = (lane >> 4) * 8;
  const int wm = (wave & 1) * 64, wn = (wave >> 1) * 64;

  for (int kt = 0; kt < K; kt += 64) {
#pragma unroll
    for (int r = 0; r < 4; ++r) {
      gll16(gA + (size_t)r * 32 * K + kt, lA + r * 32 * 64);
      gll16(gB + (size_t)r * 32 * K + kt, lB + r * 32 * 64);
    }
    asm volatile("s_waitcnt vmcnt(0)" ::: "memory");
    __syncthreads();
#pragma unroll
    for (int kk = 0; kk < 64; kk += 32) {
      short8 af[4], bfv[4];
#pragma unroll
      for (int i = 0; i < 4; ++i)
        af[i] = *(const short8*)(sA + (wm + i * 16 + fr) * 64 + kk + fk);
#pragma unroll
      for (int j = 0; j < 4; ++j)
        bfv[j] = *(const short8*)(sB + (wn + j * 16 + fr) * 64 + kk + fk);
#pragma unroll
      for (int i = 0; i < 4; ++i)
#pragma unroll
        for (int j = 0; j < 4; ++j)
          acc[i][j] = __builtin_amdgcn_mfma_f32_16x16x32_bf16(
              af[i], bfv[j], acc[i][j], 0, 0, 0);
    }
    __syncthreads();
  }

  // epilogue: C/D mapping (m89-verified): col(n)=lane&15, row(m)=(lane>>4)*4+reg
  const int col = lane & 15;
  const int row4 = (lane >> 4) * 4;
#pragma unroll
  for (int i = 0; i < 4; ++i) {
#pragma unroll
    for (int j = 0; j < 4; ++j) {
#pragma unroll
      for (int r = 0; r < 4; ++r) {
        size_t m = m0 + wm + i * 16 + row4 + r;
        int n = n0 + wn + j * 16 + col;
        float v = acc[i][j][r];
        if (OUT_BF16) {
          ((unsigned short*)Cp)[m * N + n] = f2bf(v);
        } else {
          ((float*)Cp)[m * N + n] = v + bias[n];
        }
      }
    }
  }
}

// ---------- chunked diagonal scan (3 phases) ----------
// u layout: [b][t][n] bf16. carries layout: [b][c][n] fp32.

__global__ __launch_bounds__(256) void scan_carry(
    const unsigned short* __restrict__ u, const float* __restrict__ A,
    float* __restrict__ carry) {
  const int n = blockIdx.x * 256 + threadIdx.x;
  const int c = blockIdx.y;
  const int b = blockIdx.z;
  const float a = A[n];
  size_t base = ((size_t)(b * SEQ + c * CLEN)) * DIM + n;
  float s = 0.f;
#pragma unroll 8
  for (int t = 0; t < CLEN; ++t)
    s = fmaf(a, s, bf2f(u[base + (size_t)t * DIM]));
  carry[((size_t)b * NCHUNK + c) * DIM + n] = s;
}

__global__ __launch_bounds__(256) void scan_combine(
    float* __restrict__ carry, const float* __restrict__ A) {
  const int id = blockIdx.x * 256 + threadIdx.x;  // 0..8191
  const int b = id >> 10, n = id & (DIM - 1);
  float a = A[n];
  float aL = a;
#pragma unroll
  for (int i = 0; i < 6; ++i) aL *= aL;  // a^64 == a^CLEN
  float s = 0.f;
  for (int c = 0; c < NCHUNK; ++c) {
    size_t idx = ((size_t)b * NCHUNK + c) * DIM + n;
    float local = carry[idx];
    carry[idx] = s;            // carry-in (h at end of chunk c-1)
    s = fmaf(aL, s, local);    // h_end(c) = local(c) + a^L * h_end(c-1)
  }
}

__global__ __launch_bounds__(256) void scan_apply(
    unsigned short* __restrict__ u, const float* __restrict__ A,
    const float* __restrict__ carry) {
  const int n = blockIdx.x * 256 + threadIdx.x;
  const int c = blockIdx.y;
  const int b = blockIdx.z;
  const float a = A[n];
  float s = carry[((size_t)b * NCHUNK + c) * DIM + n];
  size_t base = ((size_t)(b * SEQ + c * CLEN)) * DIM + n;
#pragma unroll 8
  for (int t = 0; t < CLEN; ++t) {
    size_t idx = base + (size_t)t * DIM;
    s = fmaf(a, s, bf2f(u[idx]));
    u[idx] = f2bf(s);  // h overwrites u in place (each elem read-then-write once)
  }
}

// ---------- launcher ----------

extern "C" void kernel_launch(void* const* d_in, const int* in_sizes, int n_in,
                              void* d_out, int out_size, void* d_ws,
                              size_t ws_size, hipStream_t stream) {
  const float* x    = (const float*)d_in[0];  // [8,2048,1024]
  const float* A    = (const float*)d_in[1];  // [1024]
  const float* B    = (const float*)d_in[2];  // [1024,1024] (n,d)
  const float* W    = (const float*)d_in[3];  // [1024,1024] (o,n)
  const float* bias = (const float*)d_in[4];  // [1024]

  char* ws = (char*)d_ws;
  unsigned short* xb = (unsigned short*)ws;                  // 32 MB
  unsigned short* u  = (unsigned short*)(ws + 33554432);     // 32 MB (u, then h)
  unsigned short* Bb = (unsigned short*)(ws + 67108864);     //  2 MB
  unsigned short* Wb = (unsigned short*)(ws + 69206016);     //  2 MB
  float* carry       = (float*)(ws + 71303168);              //  1 MB

  // casts to bf16
  cast_f32_bf16_kernel<<<(MTOT * DIM / 8) / 256, 256, 0, stream>>>(
      x, xb, MTOT * DIM / 8);
  cast_f32_bf16_kernel<<<(DIM * DIM / 8) / 256, 256, 0, stream>>>(
      B, Bb, DIM * DIM / 8);
  cast_f32_bf16_kernel<<<(DIM * DIM / 8) / 256, 256, 0, stream>>>(
      W, Wb, DIM * DIM / 8);

  // u = x . B^T  (bf16 out)
  gemm_nt<true><<<dim3(DIM / 128, MTOT / 128), 256, 0, stream>>>(
      xb, Bb, (void*)u, nullptr, DIM, DIM);

  // diagonal scan over seq (chunked, fp32 state)
  scan_carry<<<dim3(DIM / 256, NCHUNK, BATCH), 256, 0, stream>>>(u, A, carry);
  scan_combine<<<dim3((BATCH * DIM) / 256), 256, 0, stream>>>(carry, A);
  scan_apply<<<dim3(DIM / 256, NCHUNK, BATCH), 256, 0, stream>>>(u, A, carry);

  // y = h . W^T + b  (fp32 out)
  gemm_nt<false><<<dim3(DIM / 128, MTOT / 128), 256, 0, stream>>>(
      u, Wb, d_out, bias, DIM, DIM);
}

// Round 2
// 236.891 us; speedup vs baseline: 1.0876x; 1.0876x over previous
//
#include <hip/hip_runtime.h>
#include <stdint.h>

#define BATCH 8
#define SEQ 2048
#define DIM 1024
#define MTOT (BATCH * SEQ)   // 16384
#define NCHUNK 64
#define CLEN (SEQ / NCHUNK)  // 32

typedef __attribute__((ext_vector_type(8))) short short8;
typedef __attribute__((ext_vector_type(8))) unsigned short ushort8;
typedef __attribute__((ext_vector_type(4))) float floatx4;

// ---------- helpers ----------

__device__ __forceinline__ unsigned short f2bf(float f) {
  union { float f; unsigned u; } c; c.f = f;
  unsigned u = c.u;
  return (unsigned short)((u + 0x7FFFu + ((u >> 16) & 1u)) >> 16);
}
__device__ __forceinline__ float bf2f(unsigned short h) {
  union { unsigned u; float f; } c; c.u = ((unsigned)h) << 16;
  return c.f;
}

__device__ __forceinline__ void gll16(const void* g, void* l) {
  __builtin_amdgcn_global_load_lds(
      (__attribute__((address_space(1))) void*)(uintptr_t)g,
      (__attribute__((address_space(3))) void*)(uintptr_t)l,
      16, 0, 0);
}

// ---------- fused cast fp32 -> bf16 for x, B, W (8 elems/thread) ----------

#define XN8 (MTOT * DIM / 8)   // 2097152
#define MN8 (DIM * DIM / 8)    // 131072

__global__ __launch_bounds__(256) void cast3_kernel(
    const float* __restrict__ x, const float* __restrict__ B,
    const float* __restrict__ W, unsigned short* __restrict__ xb,
    unsigned short* __restrict__ Bb, unsigned short* __restrict__ Wb) {
  int i = blockIdx.x * 256 + threadIdx.x;
  const float* src;
  unsigned short* dst;
  int li;
  if (i < XN8) {
    src = x; dst = xb; li = i;
  } else if (i < XN8 + MN8) {
    src = B; dst = Bb; li = i - XN8;
  } else {
    src = W; dst = Wb; li = i - XN8 - MN8;
  }
  const float4* s4 = (const float4*)src;
  float4 a = s4[2 * li], b = s4[2 * li + 1];
  uint4 o;
  o.x = (unsigned)f2bf(a.x) | ((unsigned)f2bf(a.y) << 16);
  o.y = (unsigned)f2bf(a.z) | ((unsigned)f2bf(a.w) << 16);
  o.z = (unsigned)f2bf(b.x) | ((unsigned)f2bf(b.y) << 16);
  o.w = (unsigned)f2bf(b.z) | ((unsigned)f2bf(b.w) << 16);
  ((uint4*)dst)[li] = o;
}

// ---------- NT GEMM: C[m][n] = sum_k A[m][k]*B[n][k]
// 128x128 tile, BK=64, 256 threads (4 waves), 16x16x32 bf16 MFMA.
// LDS layout is XOR-swizzled: LDS[row][cb] holds A[row][cb ^ (row&7)]
// (in 16B/8-elem column blocks) -- achieved by swizzling the *global source*
// column per lane, since global_load_lds writes lane-contiguously.

template <bool OUT_BF16>
__global__ __launch_bounds__(256) void gemm_nt(
    const unsigned short* __restrict__ A,  // [M x K] bf16
    const unsigned short* __restrict__ B,  // [N x K] bf16
    void* __restrict__ Cp,                 // bf16 [MxN] or fp32 [MxN]
    const float* __restrict__ bias,        // used when !OUT_BF16
    int K, int N) {
  __shared__ unsigned short smem[16384];  // 32 KB: sA(16K)|sB(16K), reused as sC
  unsigned short* sA = smem;
  unsigned short* sB = smem + 8192;

  const int tid = threadIdx.x;
  const int wave = tid >> 6, lane = tid & 63;

  // XCD-aware tile remap: XCD = id&7 owns a 16-m-tile band x all 8 n-tiles,
  // n fastest so the A sub-tile is L2-hot across its 8 n reuses.
  const int id = blockIdx.x;
  const int xcd = id & 7, j = id >> 3;
  const int mt = xcd * 16 + (j >> 3);
  const int nt = j & 7;
  const size_t m0 = (size_t)mt * 128;
  const int n0 = nt * 128;

  floatx4 acc[4][4] = {};

  // staging: round r covers rows r*32 + wave*8 + (lane>>3); 16B per lane.
  // swizzled source column block: (lane&7) ^ (row&7), row&7 == (lane>>3)&7.
  const int srow = wave * 8 + (lane >> 3);
  const int scol = (((lane & 7) ^ ((lane >> 3) & 7)) * 8);
  const unsigned short* gA = A + (m0 + srow) * (size_t)K + scol;
  const unsigned short* gB = B + ((size_t)n0 + srow) * (size_t)K + scol;
  unsigned short* lA = sA + wave * 8 * 64;
  unsigned short* lB = sB + wave * 8 * 64;

  // fragment addressing: A-operand lane l holds A[m=l&15][k=(l>>4)*8+j]
  const int fr = lane & 15;
  const int frs = fr & 7;
  const int kb = lane >> 4;  // 0..3
  const int wm = (wave & 1) * 64, wn = (wave >> 1) * 64;

  for (int kt = 0; kt < K; kt += 64) {
#pragma unroll
    for (int r = 0; r < 4; ++r) {
      gll16(gA + (size_t)r * 32 * K + kt, lA + r * 32 * 64);
      gll16(gB + (size_t)r * 32 * K + kt, lB + r * 32 * 64);
    }
    asm volatile("s_waitcnt vmcnt(0)" ::: "memory");
    __syncthreads();
#pragma unroll
    for (int kk = 0; kk < 64; kk += 32) {
      short8 af[4], bfv[4];
#pragma unroll
      for (int i = 0; i < 4; ++i)
        af[i] = *(const short8*)(sA + (wm + i * 16 + fr) * 64 +
                                 ((((kk >> 3) + kb) ^ frs) * 8));
#pragma unroll
      for (int jj = 0; jj < 4; ++jj)
        bfv[jj] = *(const short8*)(sB + (wn + jj * 16 + fr) * 64 +
                                   ((((kk >> 3) + kb) ^ frs) * 8));
#pragma unroll
      for (int i = 0; i < 4; ++i)
#pragma unroll
        for (int jj = 0; jj < 4; ++jj)
          acc[i][jj] = __builtin_amdgcn_mfma_f32_16x16x32_bf16(
              af[i], bfv[jj], acc[i][jj], 0, 0, 0);
    }
    __syncthreads();
  }

  // C/D mapping (m89-verified): col(n)=lane&15, row(m)=(lane>>4)*4+reg
  const int col = lane & 15;
  const int row4 = (lane >> 4) * 4;

  if (OUT_BF16) {
    // LDS-bounce epilogue: stage 128x128 bf16 tile, then coalesced 16B stores.
    unsigned short* sC = smem;  // 16384 ushorts = exactly the tile
#pragma unroll
    for (int i = 0; i < 4; ++i)
#pragma unroll
      for (int jj = 0; jj < 4; ++jj)
#pragma unroll
        for (int r = 0; r < 4; ++r)
          sC[(wm + i * 16 + row4 + r) * 128 + wn + jj * 16 + col] =
              f2bf(acc[i][jj][r]);
    __syncthreads();
    unsigned short* C = (unsigned short*)Cp;
#pragma unroll
    for (int s = 0; s < 8; ++s) {
      int row = wave * 32 + s * 4 + (lane >> 4);
      int c8 = (lane & 15) * 8;
      *(ushort8*)(C + (m0 + row) * (size_t)N + n0 + c8) =
          *(const ushort8*)(sC + row * 128 + c8);
    }
  } else {
    float* C = (float*)Cp;
#pragma unroll
    for (int i = 0; i < 4; ++i) {
#pragma unroll
      for (int jj = 0; jj < 4; ++jj) {
#pragma unroll
        for (int r = 0; r < 4; ++r) {
          size_t m = m0 + wm + i * 16 + row4 + r;
          int n = n0 + wn + jj * 16 + col;
          C[m * N + n] = acc[i][jj][r] + bias[n];
        }
      }
    }
  }
}

// ---------- chunked diagonal scan, vectorized x8 over n ----------
// u: [b][t][n] bf16 (in-place -> h). carry: [b][c][n] fp32.

__global__ __launch_bounds__(256) void scan_carry(
    const unsigned short* __restrict__ u, const float* __restrict__ A,
    float* __restrict__ carry) {
  const int n0 = threadIdx.x * 8;          // 128 threads in x
  const int c = blockIdx.x * 2 + threadIdx.y;
  const int b = blockIdx.y;
  float a[8], s[8];
  *(float4*)&a[0] = *(const float4*)(A + n0);
  *(float4*)&a[4] = *(const float4*)(A + n0 + 4);
#pragma unroll
  for (int i = 0; i < 8; ++i) s[i] = 0.f;
  size_t base = ((size_t)(b * SEQ + c * CLEN)) * DIM + n0;
#pragma unroll 4
  for (int t = 0; t < CLEN; ++t) {
    ushort8 v = *(const ushort8*)(u + base + (size_t)t * DIM);
#pragma unroll
    for (int i = 0; i < 8; ++i) s[i] = fmaf(a[i], s[i], bf2f(v[i]));
  }
  float* dst = carry + ((size_t)b * NCHUNK + c) * DIM + n0;
  *(float4*)dst = *(float4*)&s[0];
  *(float4*)(dst + 4) = *(float4*)&s[4];
}

__global__ __launch_bounds__(256) void scan_combine(
    float* __restrict__ carry, const float* __restrict__ A) {
  const int id = blockIdx.x * 256 + threadIdx.x;  // 0..8191
  const int b = id >> 10, n = id & (DIM - 1);
  float a = A[n];
  float aL = a;
#pragma unroll
  for (int i = 0; i < 5; ++i) aL *= aL;  // a^32 == a^CLEN
  float s = 0.f;
  for (int c = 0; c < NCHUNK; ++c) {
    size_t idx = ((size_t)b * NCHUNK + c) * DIM + n;
    float local = carry[idx];
    carry[idx] = s;            // carry-in (h at end of chunk c-1)
    s = fmaf(aL, s, local);
  }
}

__global__ __launch_bounds__(256) void scan_apply(
    unsigned short* __restrict__ u, const float* __restrict__ A,
    const float* __restrict__ carry) {
  const int n0 = threadIdx.x * 8;
  const int c = blockIdx.x * 2 + threadIdx.y;
  const int b = blockIdx.y;
  float a[8], s[8];
  *(float4*)&a[0] = *(const float4*)(A + n0);
  *(float4*)&a[4] = *(const float4*)(A + n0 + 4);
  const float* cin = carry + ((size_t)b * NCHUNK + c) * DIM + n0;
  *(float4*)&s[0] = *(const float4*)cin;
  *(float4*)&s[4] = *(const float4*)(cin + 4);
  size_t base = ((size_t)(b * SEQ + c * CLEN)) * DIM + n0;
#pragma unroll 4
  for (int t = 0; t < CLEN; ++t) {
    size_t idx = base + (size_t)t * DIM;
    ushort8 v = *(const ushort8*)(u + idx);
    ushort8 o;
#pragma unroll
    for (int i = 0; i < 8; ++i) {
      s[i] = fmaf(a[i], s[i], bf2f(v[i]));
      o[i] = f2bf(s[i]);
    }
    *(ushort8*)(u + idx) = o;
  }
}

// ---------- launcher ----------

extern "C" void kernel_launch(void* const* d_in, const int* in_sizes, int n_in,
                              void* d_out, int out_size, void* d_ws,
                              size_t ws_size, hipStream_t stream) {
  const float* x    = (const float*)d_in[0];  // [8,2048,1024]
  const float* A    = (const float*)d_in[1];  // [1024]
  const float* B    = (const float*)d_in[2];  // [1024,1024] (n,d)
  const float* W    = (const float*)d_in[3];  // [1024,1024] (o,n)
  const float* bias = (const float*)d_in[4];  // [1024]

  char* ws = (char*)d_ws;
  unsigned short* xb = (unsigned short*)ws;                  // 32 MB (dead after GEMM1)
  float* carry       = (float*)ws;                           // 2 MB, overlays xb
  unsigned short* u  = (unsigned short*)(ws + 33554432);     // 32 MB (u, then h)
  unsigned short* Bb = (unsigned short*)(ws + 67108864);     //  2 MB
  unsigned short* Wb = (unsigned short*)(ws + 69206016);     //  2 MB

  // fused casts to bf16
  cast3_kernel<<<(XN8 + 2 * MN8) / 256, 256, 0, stream>>>(x, B, W, xb, Bb, Wb);

  // u = x . B^T  (bf16 out, LDS-bounce epilogue)
  gemm_nt<true><<<(MTOT / 128) * (DIM / 128), 256, 0, stream>>>(
      xb, Bb, (void*)u, nullptr, DIM, DIM);

  // diagonal scan over seq (chunked, fp32 state). carry overlays xb (dead).
  scan_carry<<<dim3(NCHUNK / 2, BATCH), dim3(128, 2), 0, stream>>>(u, A, carry);
  scan_combine<<<(BATCH * DIM) / 256, 256, 0, stream>>>(carry, A);
  scan_apply<<<dim3(NCHUNK / 2, BATCH), dim3(128, 2), 0, stream>>>(u, A, carry);

  // y = h . W^T + b  (fp32 out)
  gemm_nt<false><<<(MTOT / 128) * (DIM / 128), 256, 0, stream>>>(
      u, Wb, d_out, bias, DIM, DIM);
}